// Round 1
// baseline (1669.915 us; speedup 1.0000x reference)
//
#include <hip/hip_runtime.h>
#include <hip/hip_fp16.h>

typedef _Float16 half2v __attribute__((ext_vector_type(2)));

#define B_ 64
#define T_ 512
#define H_ 256
#define G4_ 1024
#define IN_ 60
#define O_ 402

__device__ __forceinline__ float fdot2(unsigned int a, unsigned int b, float c) {
  return __builtin_amdgcn_fdot2(__builtin_bit_cast(half2v, a),
                                __builtin_bit_cast(half2v, b), c, false);
}

__device__ __forceinline__ unsigned int pack_h2(float a, float b) {
  unsigned short ua = __half_as_ushort(__float2half(a));
  unsigned short ub = __half_as_ushort(__float2half(b));
  return (unsigned int)ua | ((unsigned int)ub << 16);
}

__device__ __forceinline__ float sigmoid_f(float x) {
  return __fdividef(1.0f, 1.0f + __expf(-x));
}
__device__ __forceinline__ float tanh_f(float x) {
  float ax = fminf(fabsf(x) * 2.0f, 40.0f);
  float e = __expf(ax);
  float r = __fdividef(e - 1.0f, e + 1.0f);
  return copysignf(r, x);
}

// ---------------- K0: weight packing / permutation ----------------
// Gate-row permutation: packed row r' = 4*u + q  <->  original row q*256 + u
__global__ __launch_bounds__(256) void k0_pack(
    const float* __restrict__ wih, const float* __restrict__ whh,
    const float* __restrict__ bih, const float* __restrict__ bhh,
    const float* __restrict__ wfc,
    float* __restrict__ wpih, float* __restrict__ biasp,
    unsigned int* __restrict__ wreg_ws, unsigned int* __restrict__ wlds_ws,
    unsigned int* __restrict__ wfcp) {
  int idx = blockIdx.x * 256 + threadIdx.x;
  if (idx < 61440) {                       // Wp_ih[k][r'] = W_ih[orig(r')][k]
    int k = idx / 1024, rp = idx % 1024;
    int orig = (rp & 3) * 256 + (rp >> 2);
    wpih[idx] = wih[orig * IN_ + k];
  } else if (idx < 62464) {                // bias_p[r'] = b_ih[orig]+b_hh[orig]
    int rp = idx - 61440;
    int orig = (rp & 3) * 256 + (rp >> 2);
    biasp[rp] = bih[orig] + bhh[orig];
  } else if (idx < 193536) {               // W_hh -> f16 pairs, per-thread stream
    int i2 = idx - 62464;
    int l = i2 >> 9, i = i2 & 511;         // l = unit/thread, i = dword idx 0..511
    int kc = i >> 4, q = (i >> 2) & 3, p = i & 3;
    int P = kc * 4 + p;                    // k-pair index: covers k=2P,2P+1
    int row = q * 256 + l;                 // original gate row
    unsigned int pk = pack_h2(whh[row * 256 + 2 * P], whh[row * 256 + 2 * P + 1]);
    if (i < 112) {                         // kc 0..6 -> LDS region, layout [j4][l][comp]
      int j = i;
      wlds_ws[(j >> 2) * 1024 + l * 4 + (j & 3)] = pk;
    } else {                               // kc 7..31 -> register region
      int j = i - 112;
      wreg_ws[(j >> 2) * 1024 + l * 4 + (j & 3)] = pk;
    }
  } else if (idx < 244992) {               // W_fc -> f16 pairs
    int i3 = idx - 193536;
    int o = i3 >> 7, P = i3 & 127;
    wfcp[o * 128 + P] = pack_h2(wfc[o * 256 + 2 * P], wfc[o * 256 + 2 * P + 1]);
  }
}

// ---------------- K1: xg = x @ W_ih^T + b_ih + b_hh (permuted cols) ---------
template <bool F32>
__global__ __launch_bounds__(256, 2) void k1_xgemm(
    const float* __restrict__ x, const float* __restrict__ wpih,
    const float* __restrict__ biasp, void* __restrict__ xg_v) {
  __shared__ float xt[IN_ * 64];           // xt[k][bt]
  const int l = threadIdx.x, blk = blockIdx.x;
  for (int i = l; i < IN_ * 64; i += 256) {
    int k = i >> 6, bt = i & 63;
    xt[i] = x[(size_t)(blk * 64 + bt) * IN_ + k];
  }
  __syncthreads();
  float4 bias4 = *(const float4*)&biasp[4 * l];
  float* xg_f = (float*)xg_v;
  unsigned int* xg_h = (unsigned int*)xg_v;
  for (int half = 0; half < 2; ++half) {   // 2 chunks of 32 bt-rows
    float4 a[32];
#pragma unroll
    for (int j = 0; j < 32; ++j) a[j] = bias4;
    for (int k = 0; k < IN_; ++k) {
      float4 w4 = *(const float4*)&wpih[k * G4_ + 4 * l];
#pragma unroll
      for (int j4 = 0; j4 < 8; ++j4) {
        float4 xv = *(const float4*)&xt[k * 64 + half * 32 + j4 * 4];
        float xs[4] = {xv.x, xv.y, xv.z, xv.w};
#pragma unroll
        for (int jj = 0; jj < 4; ++jj) {
          float xc = xs[jj];
          float4& A = a[j4 * 4 + jj];
          A.x = fmaf(w4.x, xc, A.x); A.y = fmaf(w4.y, xc, A.y);
          A.z = fmaf(w4.z, xc, A.z); A.w = fmaf(w4.w, xc, A.w);
        }
      }
    }
#pragma unroll
    for (int j = 0; j < 32; ++j) {
      size_t bt = (size_t)blk * 64 + half * 32 + j;
      if constexpr (F32) {
        *(float4*)&xg_f[bt * G4_ + 4 * l] = a[j];
      } else {
        uint2 pk;
        pk.x = pack_h2(a[j].x, a[j].y);
        pk.y = pack_h2(a[j].z, a[j].w);
        *(uint2*)&xg_h[bt * (G4_ / 2) + 2 * l] = pk;
      }
    }
  }
}

// ---------------- K2: sequential LSTM, 1 block per batch row ----------------
// thread l owns unit l: gate rows 4l..4l+3 (i,f,g,o). Weights resident:
// 400 dwords (k-chunks 7..31) in VGPRs + 112 dwords (k-chunks 0..6) in LDS.
template <bool F32>
__global__ __launch_bounds__(256, 1) void k2_lstm(
    const void* __restrict__ xg_v, const uint4* __restrict__ wreg_ws,
    const uint4* __restrict__ wlds_ws, unsigned short* __restrict__ hs) {
  __shared__ uint4 wlds[28 * 256];                 // 114688 B
  __shared__ __align__(16) unsigned int hpair[2][128];  // h double buffer (f16 pairs)
  const int l = threadIdx.x;
  const int b = blockIdx.x;
  for (int j4 = 0; j4 < 28; ++j4) wlds[j4 * 256 + l] = wlds_ws[j4 * 256 + l];
  if (l < 128) hpair[0][l] = 0u;                   // h(0) = 0
  unsigned int wreg[400];
#pragma unroll
  for (int j4 = 0; j4 < 100; ++j4) {
    uint4 v = wreg_ws[j4 * 256 + l];
    wreg[j4 * 4 + 0] = v.x; wreg[j4 * 4 + 1] = v.y;
    wreg[j4 * 4 + 2] = v.z; wreg[j4 * 4 + 3] = v.w;
  }
  const float* xg_f = (const float*)xg_v;
  const unsigned int* xg_h = (const unsigned int*)xg_v;
  float4 xf; uint2 xh;
  if constexpr (F32) xf = *(const float4*)(xg_f + (size_t)b * T_ * G4_ + 4 * l);
  else               xh = *(const uint2*)(xg_h + (size_t)b * T_ * (G4_ / 2) + 2 * l);
  float c = 0.0f;
  __syncthreads();
  for (int t = 0; t < T_; ++t) {
    float a0, a1, a2, a3;
    if constexpr (F32) { a0 = xf.x; a1 = xf.y; a2 = xf.z; a3 = xf.w; }
    else {
      half2v p0 = __builtin_bit_cast(half2v, xh.x);
      half2v p1 = __builtin_bit_cast(half2v, xh.y);
      a0 = (float)p0[0]; a1 = (float)p0[1]; a2 = (float)p1[0]; a3 = (float)p1[1];
    }
    int tn = (t < T_ - 1) ? (t + 1) : t;           // prefetch next step's xg
    if constexpr (F32) xf = *(const float4*)(xg_f + (size_t)(b * T_ + tn) * G4_ + 4 * l);
    else               xh = *(const uint2*)(xg_h + (size_t)(b * T_ + tn) * (G4_ / 2) + 2 * l);
    const unsigned int* hb = hpair[t & 1];
#pragma unroll
    for (int kc = 0; kc < 32; ++kc) {              // 8 h-values per chunk
      uint4 hq = *(const uint4*)&hb[kc * 4];       // uniform addr -> LDS broadcast
      unsigned int hx0 = hq.x, hx1 = hq.y, hx2 = hq.z, hx3 = hq.w;
      unsigned int wv[16];
      if (kc < 7) {
#pragma unroll
        for (int q = 0; q < 4; ++q) {
          uint4 v = wlds[(kc * 4 + q) * 256 + l];
          wv[q * 4 + 0] = v.x; wv[q * 4 + 1] = v.y;
          wv[q * 4 + 2] = v.z; wv[q * 4 + 3] = v.w;
        }
      } else {
#pragma unroll
        for (int j = 0; j < 16; ++j) wv[j] = wreg[(kc - 7) * 16 + j];
      }
      a0 = fdot2(wv[ 0], hx0, a0); a0 = fdot2(wv[ 1], hx1, a0);
      a0 = fdot2(wv[ 2], hx2, a0); a0 = fdot2(wv[ 3], hx3, a0);
      a1 = fdot2(wv[ 4], hx0, a1); a1 = fdot2(wv[ 5], hx1, a1);
      a1 = fdot2(wv[ 6], hx2, a1); a1 = fdot2(wv[ 7], hx3, a1);
      a2 = fdot2(wv[ 8], hx0, a2); a2 = fdot2(wv[ 9], hx1, a2);
      a2 = fdot2(wv[10], hx2, a2); a2 = fdot2(wv[11], hx3, a2);
      a3 = fdot2(wv[12], hx0, a3); a3 = fdot2(wv[13], hx1, a3);
      a3 = fdot2(wv[14], hx2, a3); a3 = fdot2(wv[15], hx3, a3);
    }
    float ig = sigmoid_f(a0), fg = sigmoid_f(a1);
    float gg = tanh_f(a2),    og = sigmoid_f(a3);
    c = fg * c + ig * gg;
    float h = og * tanh_f(c);
    unsigned short hbits = __half_as_ushort(__float2half(h));
    hs[(size_t)(b * T_ + t) * H_ + l] = hbits;
    ((unsigned short*)hpair[(t & 1) ^ 1])[l] = hbits;
    __syncthreads();                               // h(t) visible to all waves
  }
}

// ---------------- K3: out = hs @ W_fc^T + b_fc ----------------
__global__ __launch_bounds__(256, 2) void k3_out(
    const unsigned short* __restrict__ hs, const unsigned int* __restrict__ wfcp,
    const float* __restrict__ bfc, float* __restrict__ out) {
  __shared__ unsigned int ht[64 * 128];            // 64 bt-rows of h (f16 pairs)
  const int l = threadIdx.x, blk = blockIdx.x;
  const unsigned int* hsrc = (const unsigned int*)hs + (size_t)blk * 64 * 128;
  for (int i = l; i < 64 * 128; i += 256) ht[i] = hsrc[i];
  __syncthreads();
  const int c1 = l;
  const int c2 = 256 + l;
  const bool has2 = (c2 < O_);
  const int c2r = has2 ? c2 : 0;
  float b1 = bfc[c1], b2 = bfc[c2r];
  for (int btc = 0; btc < 4; ++btc) {
    float a1[16], a2[16];
#pragma unroll
    for (int j = 0; j < 16; ++j) { a1[j] = b1; a2[j] = b2; }
    for (int Pc = 0; Pc < 8; ++Pc) {
      uint4 wq1[4], wq2[4];
#pragma unroll
      for (int p4 = 0; p4 < 4; ++p4) {
        wq1[p4] = *(const uint4*)&wfcp[c1 * 128 + Pc * 16 + 4 * p4];
        wq2[p4] = *(const uint4*)&wfcp[c2r * 128 + Pc * 16 + 4 * p4];
      }
#pragma unroll
      for (int j = 0; j < 16; ++j) {
        const unsigned int* hr = &ht[(btc * 16 + j) * 128 + Pc * 16];
#pragma unroll
        for (int p4 = 0; p4 < 4; ++p4) {
          uint4 hv = *(const uint4*)&hr[4 * p4];
          a1[j] = fdot2(wq1[p4].x, hv.x, a1[j]);
          a1[j] = fdot2(wq1[p4].y, hv.y, a1[j]);
          a1[j] = fdot2(wq1[p4].z, hv.z, a1[j]);
          a1[j] = fdot2(wq1[p4].w, hv.w, a1[j]);
          a2[j] = fdot2(wq2[p4].x, hv.x, a2[j]);
          a2[j] = fdot2(wq2[p4].y, hv.y, a2[j]);
          a2[j] = fdot2(wq2[p4].z, hv.z, a2[j]);
          a2[j] = fdot2(wq2[p4].w, hv.w, a2[j]);
        }
      }
    }
#pragma unroll
    for (int j = 0; j < 16; ++j) {
      size_t bt = (size_t)blk * 64 + btc * 16 + j;
      out[bt * O_ + c1] = a1[j];
      if (has2) out[bt * O_ + c2] = a2[j];
    }
  }
}

// ---------------- host ----------------
extern "C" void kernel_launch(void* const* d_in, const int* in_sizes, int n_in,
                              void* d_out, int out_size, void* d_ws, size_t ws_size,
                              hipStream_t stream) {
  const float* x   = (const float*)d_in[0];
  const float* wih = (const float*)d_in[1];
  const float* whh = (const float*)d_in[2];
  const float* bih = (const float*)d_in[3];
  const float* bhh = (const float*)d_in[4];
  const float* wfc = (const float*)d_in[5];
  const float* bfc = (const float*)d_in[6];
  float* out = (float*)d_out;
  char* ws = (char*)d_ws;

  const size_t HS_BYTES = (size_t)B_ * T_ * H_ * 2;
  const size_t XG_F32   = (size_t)B_ * T_ * G4_ * 4;
  const size_t WREG_B   = 100 * 256 * 16;
  const size_t WLDS_B   = 28 * 256 * 16;
  const size_t WPIH_B   = (size_t)IN_ * G4_ * 4;
  const size_t BIAS_B   = (size_t)G4_ * 4;
  const size_t WFCP_B   = (size_t)O_ * 128 * 4;
  const size_t TAIL = HS_BYTES + WREG_B + WLDS_B + WPIH_B + BIAS_B + WFCP_B;

  bool f32xg = (ws_size >= XG_F32 + TAIL);
  size_t xg_bytes = f32xg ? XG_F32 : ((size_t)B_ * T_ * G4_ * 2);

  char* xg    = ws;
  char* hsb   = ws + xg_bytes;
  char* wregp = hsb + HS_BYTES;
  char* wldsp = wregp + WREG_B;
  char* wpihp = wldsp + WLDS_B;
  char* biasp = wpihp + WPIH_B;
  char* wfcpp = biasp + BIAS_B;

  hipLaunchKernelGGL(k0_pack, dim3(957), dim3(256), 0, stream,
                     wih, whh, bih, bhh, wfc,
                     (float*)wpihp, (float*)biasp,
                     (unsigned int*)wregp, (unsigned int*)wldsp,
                     (unsigned int*)wfcpp);
  if (f32xg) {
    hipLaunchKernelGGL((k1_xgemm<true>), dim3(512), dim3(256), 0, stream,
                       x, (const float*)wpihp, (const float*)biasp, (void*)xg);
    hipLaunchKernelGGL((k2_lstm<true>), dim3(64), dim3(256), 0, stream,
                       (const void*)xg, (const uint4*)wregp, (const uint4*)wldsp,
                       (unsigned short*)hsb);
  } else {
    hipLaunchKernelGGL((k1_xgemm<false>), dim3(512), dim3(256), 0, stream,
                       x, (const float*)wpihp, (const float*)biasp, (void*)xg);
    hipLaunchKernelGGL((k2_lstm<false>), dim3(64), dim3(256), 0, stream,
                       (const void*)xg, (const uint4*)wregp, (const uint4*)wldsp,
                       (unsigned short*)hsb);
  }
  hipLaunchKernelGGL(k3_out, dim3(512), dim3(256), 0, stream,
                     (const unsigned short*)hsb, (const unsigned int*)wfcpp,
                     bfc, out);
}

// Round 2
// 1416.461 us; speedup vs baseline: 1.1789x; 1.1789x over previous
//
#include <hip/hip_runtime.h>
#include <hip/hip_fp16.h>

typedef _Float16 half2v __attribute__((ext_vector_type(2)));

#define B_ 64
#define T_ 512
#define H_ 256
#define G4_ 1024
#define IN_ 60
#define O_ 402

__device__ __forceinline__ float fdot2(unsigned int a, unsigned int b, float c) {
  return __builtin_amdgcn_fdot2(__builtin_bit_cast(half2v, a),
                                __builtin_bit_cast(half2v, b), c, false);
}

__device__ __forceinline__ unsigned int pack_h2(float a, float b) {
  unsigned short ua = __half_as_ushort(__float2half(a));
  unsigned short ub = __half_as_ushort(__float2half(b));
  return (unsigned int)ua | ((unsigned int)ub << 16);
}

__device__ __forceinline__ float sigmoid_f(float x) {
  return __fdividef(1.0f, 1.0f + __expf(-x));
}
__device__ __forceinline__ float tanh_f(float x) {
  float ax = fminf(fabsf(x) * 2.0f, 40.0f);
  float e = __expf(ax);
  float r = __fdividef(e - 1.0f, e + 1.0f);
  return copysignf(r, x);
}

// ---------------- K0: weight packing / permutation ----------------
// Gate-row permutation: packed row r' = 4*u + q  <->  original row q*256 + u
__global__ __launch_bounds__(256) void k0_pack(
    const float* __restrict__ wih, const float* __restrict__ whh,
    const float* __restrict__ bih, const float* __restrict__ bhh,
    const float* __restrict__ wfc,
    float* __restrict__ wpih, float* __restrict__ biasp,
    unsigned int* __restrict__ wreg_ws, unsigned int* __restrict__ wlds_ws,
    unsigned int* __restrict__ wfcp) {
  int idx = blockIdx.x * 256 + threadIdx.x;
  if (idx < 61440) {                       // Wp_ih[k][r'] = W_ih[orig(r')][k]
    int k = idx / 1024, rp = idx % 1024;
    int orig = (rp & 3) * 256 + (rp >> 2);
    wpih[idx] = wih[orig * IN_ + k];
  } else if (idx < 62464) {                // bias_p[r'] = b_ih[orig]+b_hh[orig]
    int rp = idx - 61440;
    int orig = (rp & 3) * 256 + (rp >> 2);
    biasp[rp] = bih[orig] + bhh[orig];
  } else if (idx < 193536) {               // W_hh -> f16 pairs, per-thread stream
    int i2 = idx - 62464;
    int l = i2 >> 9, i = i2 & 511;         // l = unit/thread, i = dword idx 0..511
    int kc = i >> 4, q = (i >> 2) & 3, p = i & 3;
    int P = kc * 4 + p;                    // k-pair index: covers k=2P,2P+1
    int row = q * 256 + l;                 // original gate row
    unsigned int pk = pack_h2(whh[row * 256 + 2 * P], whh[row * 256 + 2 * P + 1]);
    if (i < 112) {                         // kc 0..6 -> LDS region, layout [j4][l][comp]
      int j = i;
      wlds_ws[(j >> 2) * 1024 + l * 4 + (j & 3)] = pk;
    } else {                               // kc 7..31 -> register region
      int j = i - 112;
      wreg_ws[(j >> 2) * 1024 + l * 4 + (j & 3)] = pk;
    }
  } else if (idx < 244992) {               // W_fc -> f16 pairs
    int i3 = idx - 193536;
    int o = i3 >> 7, P = i3 & 127;
    wfcp[o * 128 + P] = pack_h2(wfc[o * 256 + 2 * P], wfc[o * 256 + 2 * P + 1]);
  }
}

// ---------------- K1: xg = x @ W_ih^T + b_ih + b_hh (permuted cols) ---------
template <bool F32>
__global__ __launch_bounds__(256, 2) void k1_xgemm(
    const float* __restrict__ x, const float* __restrict__ wpih,
    const float* __restrict__ biasp, void* __restrict__ xg_v) {
  __shared__ float xt[IN_ * 64];           // xt[k][bt]
  const int l = threadIdx.x, blk = blockIdx.x;
  for (int i = l; i < IN_ * 64; i += 256) {
    int k = i >> 6, bt = i & 63;
    xt[i] = x[(size_t)(blk * 64 + bt) * IN_ + k];
  }
  __syncthreads();
  float4 bias4 = *(const float4*)&biasp[4 * l];
  float* xg_f = (float*)xg_v;
  unsigned int* xg_h = (unsigned int*)xg_v;
  for (int half = 0; half < 2; ++half) {   // 2 chunks of 32 bt-rows
    float4 a[32];
#pragma unroll
    for (int j = 0; j < 32; ++j) a[j] = bias4;
    for (int k = 0; k < IN_; ++k) {
      float4 w4 = *(const float4*)&wpih[k * G4_ + 4 * l];
#pragma unroll
      for (int j4 = 0; j4 < 8; ++j4) {
        float4 xv = *(const float4*)&xt[k * 64 + half * 32 + j4 * 4];
        float xs[4] = {xv.x, xv.y, xv.z, xv.w};
#pragma unroll
        for (int jj = 0; jj < 4; ++jj) {
          float xc = xs[jj];
          float4& A = a[j4 * 4 + jj];
          A.x = fmaf(w4.x, xc, A.x); A.y = fmaf(w4.y, xc, A.y);
          A.z = fmaf(w4.z, xc, A.z); A.w = fmaf(w4.w, xc, A.w);
        }
      }
    }
#pragma unroll
    for (int j = 0; j < 32; ++j) {
      size_t bt = (size_t)blk * 64 + half * 32 + j;
      if constexpr (F32) {
        *(float4*)&xg_f[bt * G4_ + 4 * l] = a[j];
      } else {
        uint2 pk;
        pk.x = pack_h2(a[j].x, a[j].y);
        pk.y = pack_h2(a[j].z, a[j].w);
        *(uint2*)&xg_h[bt * (G4_ / 2) + 2 * l] = pk;
      }
    }
  }
}

// ---------------- K2: sequential LSTM, 1 block per batch row ----------------
// thread l owns unit l: gate rows 4l..4l+3 (i,f,g,o). W_hh residency per thread
// (512 f16-pair dwords): kc 0..6 (112 dw) in LDS, kc 7..21 (240 dw) in AGPRs
// (explicit v_accvgpr asm with "a" constraints), kc 22..31 (160 dw) in VGPRs.
template <bool F32>
__global__ __launch_bounds__(256, 1) void k2_lstm(
    const void* __restrict__ xg_v, const uint4* __restrict__ wreg_ws,
    const uint4* __restrict__ wlds_ws, unsigned short* __restrict__ hs) {
  __shared__ uint4 wlds[28 * 256];                 // 114688 B
  __shared__ __align__(16) unsigned int hpair[2][128];  // h double buffer (f16 pairs)
  const int l = threadIdx.x;
  const int b = blockIdx.x;
  for (int j4 = 0; j4 < 28; ++j4) wlds[j4 * 256 + l] = wlds_ws[j4 * 256 + l];
  if (l < 128) hpair[0][l] = 0u;                   // h(0) = 0

  // AGPR region: kc 7..21 -> wreg_ws stream j4 = 0..59 (dwords 0..239)
  unsigned int wa[240];
#pragma unroll
  for (int j4 = 0; j4 < 60; ++j4) {
    uint4 v = wreg_ws[j4 * 256 + l];
    asm volatile("v_accvgpr_write_b32 %0, %1" : "=a"(wa[4 * j4 + 0]) : "v"(v.x));
    asm volatile("v_accvgpr_write_b32 %0, %1" : "=a"(wa[4 * j4 + 1]) : "v"(v.y));
    asm volatile("v_accvgpr_write_b32 %0, %1" : "=a"(wa[4 * j4 + 2]) : "v"(v.z));
    asm volatile("v_accvgpr_write_b32 %0, %1" : "=a"(wa[4 * j4 + 3]) : "v"(v.w));
  }
  // VGPR region: kc 22..31 -> wreg_ws stream j4 = 60..99 (dwords 240..399)
  unsigned int wreg[160];
#pragma unroll
  for (int j4 = 0; j4 < 40; ++j4) {
    uint4 v = wreg_ws[(60 + j4) * 256 + l];
    wreg[j4 * 4 + 0] = v.x; wreg[j4 * 4 + 1] = v.y;
    wreg[j4 * 4 + 2] = v.z; wreg[j4 * 4 + 3] = v.w;
  }

  const float* xg_f = (const float*)xg_v;
  const unsigned int* xg_h = (const unsigned int*)xg_v;
  float4 xf; uint2 xh;
  if constexpr (F32) xf = *(const float4*)(xg_f + (size_t)b * T_ * G4_ + 4 * l);
  else               xh = *(const uint2*)(xg_h + (size_t)b * T_ * (G4_ / 2) + 2 * l);
  float c = 0.0f;
  __syncthreads();
  for (int t = 0; t < T_; ++t) {
    float a0, a1, a2, a3;
    if constexpr (F32) { a0 = xf.x; a1 = xf.y; a2 = xf.z; a3 = xf.w; }
    else {
      half2v p0 = __builtin_bit_cast(half2v, xh.x);
      half2v p1 = __builtin_bit_cast(half2v, xh.y);
      a0 = (float)p0[0]; a1 = (float)p0[1]; a2 = (float)p1[0]; a3 = (float)p1[1];
    }
    int tn = (t < T_ - 1) ? (t + 1) : t;           // prefetch next step's xg
    if constexpr (F32) xf = *(const float4*)(xg_f + (size_t)(b * T_ + tn) * G4_ + 4 * l);
    else               xh = *(const uint2*)(xg_h + (size_t)(b * T_ + tn) * (G4_ / 2) + 2 * l);
    const unsigned int* hb = hpair[t & 1];
#pragma unroll
    for (int kc = 0; kc < 32; ++kc) {              // 8 h-values per chunk
      uint4 hq = *(const uint4*)&hb[kc * 4];       // uniform addr -> LDS broadcast
      unsigned int hx0 = hq.x, hx1 = hq.y, hx2 = hq.z, hx3 = hq.w;
      unsigned int wv[16];
      if (kc < 7) {                                // LDS region
#pragma unroll
        for (int q = 0; q < 4; ++q) {
          uint4 v = wlds[(kc * 4 + q) * 256 + l];
          wv[q * 4 + 0] = v.x; wv[q * 4 + 1] = v.y;
          wv[q * 4 + 2] = v.z; wv[q * 4 + 3] = v.w;
        }
      } else if (kc < 22) {                        // AGPR region
#pragma unroll
        for (int j = 0; j < 16; ++j)
          asm volatile("v_accvgpr_read_b32 %0, %1"
                       : "=v"(wv[j]) : "a"(wa[(kc - 7) * 16 + j]));
      } else {                                     // VGPR region
#pragma unroll
        for (int j = 0; j < 16; ++j) wv[j] = wreg[(kc - 22) * 16 + j];
      }
      a0 = fdot2(wv[ 0], hx0, a0); a0 = fdot2(wv[ 1], hx1, a0);
      a0 = fdot2(wv[ 2], hx2, a0); a0 = fdot2(wv[ 3], hx3, a0);
      a1 = fdot2(wv[ 4], hx0, a1); a1 = fdot2(wv[ 5], hx1, a1);
      a1 = fdot2(wv[ 6], hx2, a1); a1 = fdot2(wv[ 7], hx3, a1);
      a2 = fdot2(wv[ 8], hx0, a2); a2 = fdot2(wv[ 9], hx1, a2);
      a2 = fdot2(wv[10], hx2, a2); a2 = fdot2(wv[11], hx3, a2);
      a3 = fdot2(wv[12], hx0, a3); a3 = fdot2(wv[13], hx1, a3);
      a3 = fdot2(wv[14], hx2, a3); a3 = fdot2(wv[15], hx3, a3);
    }
    float ig = sigmoid_f(a0), fg = sigmoid_f(a1);
    float gg = tanh_f(a2),    og = sigmoid_f(a3);
    c = fg * c + ig * gg;
    float h = og * tanh_f(c);
    unsigned short hbits = __half_as_ushort(__float2half(h));
    hs[(size_t)(b * T_ + t) * H_ + l] = hbits;
    ((unsigned short*)hpair[(t & 1) ^ 1])[l] = hbits;
    __syncthreads();                               // h(t) visible to all waves
  }
}

// ---------------- K3: out = hs @ W_fc^T + b_fc ----------------
__global__ __launch_bounds__(256, 2) void k3_out(
    const unsigned short* __restrict__ hs, const unsigned int* __restrict__ wfcp,
    const float* __restrict__ bfc, float* __restrict__ out) {
  __shared__ unsigned int ht[64 * 128];            // 64 bt-rows of h (f16 pairs)
  const int l = threadIdx.x, blk = blockIdx.x;
  const unsigned int* hsrc = (const unsigned int*)hs + (size_t)blk * 64 * 128;
  for (int i = l; i < 64 * 128; i += 256) ht[i] = hsrc[i];
  __syncthreads();
  const int c1 = l;
  const int c2 = 256 + l;
  const bool has2 = (c2 < O_);
  const int c2r = has2 ? c2 : 0;
  float b1 = bfc[c1], b2 = bfc[c2r];
  for (int btc = 0; btc < 4; ++btc) {
    float a1[16], a2[16];
#pragma unroll
    for (int j = 0; j < 16; ++j) { a1[j] = b1; a2[j] = b2; }
    for (int Pc = 0; Pc < 8; ++Pc) {
      uint4 wq1[4], wq2[4];
#pragma unroll
      for (int p4 = 0; p4 < 4; ++p4) {
        wq1[p4] = *(const uint4*)&wfcp[c1 * 128 + Pc * 16 + 4 * p4];
        wq2[p4] = *(const uint4*)&wfcp[c2r * 128 + Pc * 16 + 4 * p4];
      }
#pragma unroll
      for (int j = 0; j < 16; ++j) {
        const unsigned int* hr = &ht[(btc * 16 + j) * 128 + Pc * 16];
#pragma unroll
        for (int p4 = 0; p4 < 4; ++p4) {
          uint4 hv = *(const uint4*)&hr[4 * p4];
          a1[j] = fdot2(wq1[p4].x, hv.x, a1[j]);
          a1[j] = fdot2(wq1[p4].y, hv.y, a1[j]);
          a1[j] = fdot2(wq1[p4].z, hv.z, a1[j]);
          a1[j] = fdot2(wq1[p4].w, hv.w, a1[j]);
          a2[j] = fdot2(wq2[p4].x, hv.x, a2[j]);
          a2[j] = fdot2(wq2[p4].y, hv.y, a2[j]);
          a2[j] = fdot2(wq2[p4].z, hv.z, a2[j]);
          a2[j] = fdot2(wq2[p4].w, hv.w, a2[j]);
        }
      }
    }
#pragma unroll
    for (int j = 0; j < 16; ++j) {
      size_t bt = (size_t)blk * 64 + btc * 16 + j;
      out[bt * O_ + c1] = a1[j];
      if (has2) out[bt * O_ + c2] = a2[j];
    }
  }
}

// ---------------- host ----------------
extern "C" void kernel_launch(void* const* d_in, const int* in_sizes, int n_in,
                              void* d_out, int out_size, void* d_ws, size_t ws_size,
                              hipStream_t stream) {
  const float* x   = (const float*)d_in[0];
  const float* wih = (const float*)d_in[1];
  const float* whh = (const float*)d_in[2];
  const float* bih = (const float*)d_in[3];
  const float* bhh = (const float*)d_in[4];
  const float* wfc = (const float*)d_in[5];
  const float* bfc = (const float*)d_in[6];
  float* out = (float*)d_out;
  char* ws = (char*)d_ws;

  const size_t HS_BYTES = (size_t)B_ * T_ * H_ * 2;
  const size_t XG_F32   = (size_t)B_ * T_ * G4_ * 4;
  const size_t WREG_B   = 100 * 256 * 16;
  const size_t WLDS_B   = 28 * 256 * 16;
  const size_t WPIH_B   = (size_t)IN_ * G4_ * 4;
  const size_t BIAS_B   = (size_t)G4_ * 4;
  const size_t WFCP_B   = (size_t)O_ * 128 * 4;
  const size_t TAIL = HS_BYTES + WREG_B + WLDS_B + WPIH_B + BIAS_B + WFCP_B;

  bool f32xg = (ws_size >= XG_F32 + TAIL);
  size_t xg_bytes = f32xg ? XG_F32 : ((size_t)B_ * T_ * G4_ * 2);

  char* xg    = ws;
  char* hsb   = ws + xg_bytes;
  char* wregp = hsb + HS_BYTES;
  char* wldsp = wregp + WREG_B;
  char* wpihp = wldsp + WLDS_B;
  char* biasp = wpihp + WPIH_B;
  char* wfcpp = biasp + BIAS_B;

  hipLaunchKernelGGL(k0_pack, dim3(957), dim3(256), 0, stream,
                     wih, whh, bih, bhh, wfc,
                     (float*)wpihp, (float*)biasp,
                     (unsigned int*)wregp, (unsigned int*)wldsp,
                     (unsigned int*)wfcpp);
  if (f32xg) {
    hipLaunchKernelGGL((k1_xgemm<true>), dim3(512), dim3(256), 0, stream,
                       x, (const float*)wpihp, (const float*)biasp, (void*)xg);
    hipLaunchKernelGGL((k2_lstm<true>), dim3(64), dim3(256), 0, stream,
                       (const void*)xg, (const uint4*)wregp, (const uint4*)wldsp,
                       (unsigned short*)hsb);
  } else {
    hipLaunchKernelGGL((k1_xgemm<false>), dim3(512), dim3(256), 0, stream,
                       x, (const float*)wpihp, (const float*)biasp, (void*)xg);
    hipLaunchKernelGGL((k2_lstm<false>), dim3(64), dim3(256), 0, stream,
                       (const void*)xg, (const uint4*)wregp, (const uint4*)wldsp,
                       (unsigned short*)hsb);
  }
  hipLaunchKernelGGL(k3_out, dim3(512), dim3(256), 0, stream,
                     (const unsigned short*)hsb, (const unsigned int*)wfcpp,
                     bfc, out);
}

// Round 3
// 1271.052 us; speedup vs baseline: 1.3138x; 1.1144x over previous
//
#include <hip/hip_runtime.h>
#include <hip/hip_fp16.h>

typedef _Float16 half2v __attribute__((ext_vector_type(2)));

#define B_ 64
#define T_ 512
#define H_ 256
#define G4_ 1024
#define IN_ 60
#define O_ 402

__device__ __forceinline__ float fdot2(unsigned int a, unsigned int b, float c) {
  return __builtin_amdgcn_fdot2(__builtin_bit_cast(half2v, a),
                                __builtin_bit_cast(half2v, b), c, false);
}

__device__ __forceinline__ unsigned int pack_h2(float a, float b) {
  unsigned short ua = __half_as_ushort(__float2half(a));
  unsigned short ub = __half_as_ushort(__float2half(b));
  return (unsigned int)ua | ((unsigned int)ub << 16);
}

__device__ __forceinline__ float sigmoid_f(float x) {
  return __fdividef(1.0f, 1.0f + __expf(-x));
}
__device__ __forceinline__ float tanh_f(float x) {
  float ax = fminf(fabsf(x) * 2.0f, 40.0f);
  float e = __expf(ax);
  float r = __fdividef(e - 1.0f, e + 1.0f);
  return copysignf(r, x);
}

// ---------------- K0: weight packing / permutation ----------------
// Gate-row permutation: packed row r' = 4*u + q  <->  original row q*256 + u
__global__ __launch_bounds__(256) void k0_pack(
    const float* __restrict__ wih, const float* __restrict__ whh,
    const float* __restrict__ bih, const float* __restrict__ bhh,
    const float* __restrict__ wfc,
    float* __restrict__ wpih, float* __restrict__ biasp,
    unsigned int* __restrict__ wreg_ws, unsigned int* __restrict__ wlds_ws,
    unsigned int* __restrict__ wfcp) {
  int idx = blockIdx.x * 256 + threadIdx.x;
  if (idx < 61440) {                       // Wp_ih[k][r'] = W_ih[orig(r')][k]
    int k = idx / 1024, rp = idx % 1024;
    int orig = (rp & 3) * 256 + (rp >> 2);
    wpih[idx] = wih[orig * IN_ + k];
  } else if (idx < 62464) {                // bias_p[r'] = b_ih[orig]+b_hh[orig]
    int rp = idx - 61440;
    int orig = (rp & 3) * 256 + (rp >> 2);
    biasp[rp] = bih[orig] + bhh[orig];
  } else if (idx < 193536) {               // W_hh -> f16 pairs, per-thread stream
    int i2 = idx - 62464;
    int l = i2 >> 9, i = i2 & 511;         // l = unit/thread, i = dword idx 0..511
    int kc = i >> 4, q = (i >> 2) & 3, p = i & 3;
    int P = kc * 4 + p;                    // k-pair index: covers k=2P,2P+1
    int row = q * 256 + l;                 // original gate row
    unsigned int pk = pack_h2(whh[row * 256 + 2 * P], whh[row * 256 + 2 * P + 1]);
    if (i < 112) {                         // kc 0..6 -> LDS region, layout [j4][l][comp]
      int j = i;
      wlds_ws[(j >> 2) * 1024 + l * 4 + (j & 3)] = pk;
    } else {                               // kc 7..31 -> register region
      int j = i - 112;
      wreg_ws[(j >> 2) * 1024 + l * 4 + (j & 3)] = pk;
    }
  } else if (idx < 244992) {               // W_fc -> f16 pairs
    int i3 = idx - 193536;
    int o = i3 >> 7, P = i3 & 127;
    wfcp[o * 128 + P] = pack_h2(wfc[o * 256 + 2 * P], wfc[o * 256 + 2 * P + 1]);
  }
}

// ---------------- K1: xg = x @ W_ih^T + b_ih + b_hh (permuted cols) ---------
template <bool F32>
__global__ __launch_bounds__(256, 2) void k1_xgemm(
    const float* __restrict__ x, const float* __restrict__ wpih,
    const float* __restrict__ biasp, void* __restrict__ xg_v) {
  __shared__ float xt[IN_ * 64];           // xt[k][bt]
  const int l = threadIdx.x, blk = blockIdx.x;
  for (int i = l; i < IN_ * 64; i += 256) {
    int k = i >> 6, bt = i & 63;
    xt[i] = x[(size_t)(blk * 64 + bt) * IN_ + k];
  }
  __syncthreads();
  float4 bias4 = *(const float4*)&biasp[4 * l];
  float* xg_f = (float*)xg_v;
  unsigned int* xg_h = (unsigned int*)xg_v;
  for (int half = 0; half < 2; ++half) {   // 2 chunks of 32 bt-rows
    float4 a[32];
#pragma unroll
    for (int j = 0; j < 32; ++j) a[j] = bias4;
    for (int k = 0; k < IN_; ++k) {
      float4 w4 = *(const float4*)&wpih[k * G4_ + 4 * l];
#pragma unroll
      for (int j4 = 0; j4 < 8; ++j4) {
        float4 xv = *(const float4*)&xt[k * 64 + half * 32 + j4 * 4];
        float xs[4] = {xv.x, xv.y, xv.z, xv.w};
#pragma unroll
        for (int jj = 0; jj < 4; ++jj) {
          float xc = xs[jj];
          float4& A = a[j4 * 4 + jj];
          A.x = fmaf(w4.x, xc, A.x); A.y = fmaf(w4.y, xc, A.y);
          A.z = fmaf(w4.z, xc, A.z); A.w = fmaf(w4.w, xc, A.w);
        }
      }
    }
#pragma unroll
    for (int j = 0; j < 32; ++j) {
      size_t bt = (size_t)blk * 64 + half * 32 + j;
      if constexpr (F32) {
        *(float4*)&xg_f[bt * G4_ + 4 * l] = a[j];
      } else {
        uint2 pk;
        pk.x = pack_h2(a[j].x, a[j].y);
        pk.y = pack_h2(a[j].z, a[j].w);
        *(uint2*)&xg_h[bt * (G4_ / 2) + 2 * l] = pk;
      }
    }
  }
}

// ---------------- K2: sequential LSTM, 1 block per batch row ----------------
// thread l owns unit l: gate rows 4l..4l+3 (i,f,g,o). W_hh residency per thread
// (512 f16-pair dwords): kc 0..6 (112 dw) in LDS, kc 7..21 (240 dw) in AGPRs,
// kc 22..31 (160 dw) in VGPRs. AGPR asms are NON-volatile (pure) so the
// scheduler can pipeline ds_reads across them; dummy "v"(t) input prevents
// LICM from hoisting 240 reads out of the t-loop. h-broadcasts software-
// pipelined 4 chunks deep.
template <bool F32>
__global__ __launch_bounds__(256, 1) void k2_lstm(
    const void* __restrict__ xg_v, const uint4* __restrict__ wreg_ws,
    const uint4* __restrict__ wlds_ws, unsigned short* __restrict__ hs) {
  __shared__ uint4 wlds[28 * 256];                 // 114688 B
  __shared__ __align__(16) unsigned int hpair[2][128];  // h double buffer (f16 pairs)
  const int l = threadIdx.x;
  const int b = blockIdx.x;
  for (int j4 = 0; j4 < 28; ++j4) wlds[j4 * 256 + l] = wlds_ws[j4 * 256 + l];
  if (l < 128) hpair[0][l] = 0u;                   // h(0) = 0

  // AGPR region: kc 7..21 -> wreg_ws stream j4 = 0..59 (dwords 0..239)
  unsigned int wa[240];
#pragma unroll
  for (int j4 = 0; j4 < 60; ++j4) {
    uint4 v = wreg_ws[j4 * 256 + l];
    asm("v_accvgpr_write_b32 %0, %1" : "=a"(wa[4 * j4 + 0]) : "v"(v.x));
    asm("v_accvgpr_write_b32 %0, %1" : "=a"(wa[4 * j4 + 1]) : "v"(v.y));
    asm("v_accvgpr_write_b32 %0, %1" : "=a"(wa[4 * j4 + 2]) : "v"(v.z));
    asm("v_accvgpr_write_b32 %0, %1" : "=a"(wa[4 * j4 + 3]) : "v"(v.w));
  }
  // VGPR region: kc 22..31 -> wreg_ws stream j4 = 60..99 (dwords 240..399)
  unsigned int wreg[160];
#pragma unroll
  for (int j4 = 0; j4 < 40; ++j4) {
    uint4 v = wreg_ws[(60 + j4) * 256 + l];
    wreg[j4 * 4 + 0] = v.x; wreg[j4 * 4 + 1] = v.y;
    wreg[j4 * 4 + 2] = v.z; wreg[j4 * 4 + 3] = v.w;
  }

  const float* xg_f = (const float*)xg_v;
  const unsigned int* xg_h = (const unsigned int*)xg_v;
  float4 xf; uint2 xh;
  if constexpr (F32) xf = *(const float4*)(xg_f + (size_t)b * T_ * G4_ + 4 * l);
  else               xh = *(const uint2*)(xg_h + (size_t)b * T_ * (G4_ / 2) + 2 * l);
  float c = 0.0f;
  __syncthreads();
  for (int t = 0; t < T_; ++t) {
    float a0, a1, a2, a3;
    if constexpr (F32) { a0 = xf.x; a1 = xf.y; a2 = xf.z; a3 = xf.w; }
    else {
      half2v p0 = __builtin_bit_cast(half2v, xh.x);
      half2v p1 = __builtin_bit_cast(half2v, xh.y);
      a0 = (float)p0[0]; a1 = (float)p0[1]; a2 = (float)p1[0]; a3 = (float)p1[1];
    }
    int tn = (t < T_ - 1) ? (t + 1) : t;           // prefetch next step's xg
    if constexpr (F32) xf = *(const float4*)(xg_f + (size_t)(b * T_ + tn) * G4_ + 4 * l);
    else               xh = *(const uint2*)(xg_h + (size_t)(b * T_ + tn) * (G4_ / 2) + 2 * l);
    const unsigned int* hb = hpair[t & 1];
    uint4 hqb[4];                                  // 4-deep broadcast pipeline
#pragma unroll
    for (int p = 0; p < 4; ++p) hqb[p] = *(const uint4*)&hb[p * 4];
#pragma unroll
    for (int kc = 0; kc < 32; ++kc) {              // 8 h-values per chunk
      uint4 hq = hqb[kc & 3];
      if (kc + 4 < 32) hqb[kc & 3] = *(const uint4*)&hb[(kc + 4) * 4];
      unsigned int hx0 = hq.x, hx1 = hq.y, hx2 = hq.z, hx3 = hq.w;
      unsigned int wv[16];
      if (kc < 7) {                                // LDS region
#pragma unroll
        for (int q = 0; q < 4; ++q) {
          uint4 v = wlds[(kc * 4 + q) * 256 + l];
          wv[q * 4 + 0] = v.x; wv[q * 4 + 1] = v.y;
          wv[q * 4 + 2] = v.z; wv[q * 4 + 3] = v.w;
        }
      } else if (kc < 22) {                        // AGPR region (pure asm)
#pragma unroll
        for (int j = 0; j < 16; ++j)
          asm("v_accvgpr_read_b32 %0, %1"
              : "=v"(wv[j]) : "a"(wa[(kc - 7) * 16 + j]), "v"(t));
      } else {                                     // VGPR region
#pragma unroll
        for (int j = 0; j < 16; ++j) wv[j] = wreg[(kc - 22) * 16 + j];
      }
      a0 = fdot2(wv[ 0], hx0, a0); a0 = fdot2(wv[ 1], hx1, a0);
      a0 = fdot2(wv[ 2], hx2, a0); a0 = fdot2(wv[ 3], hx3, a0);
      a1 = fdot2(wv[ 4], hx0, a1); a1 = fdot2(wv[ 5], hx1, a1);
      a1 = fdot2(wv[ 6], hx2, a1); a1 = fdot2(wv[ 7], hx3, a1);
      a2 = fdot2(wv[ 8], hx0, a2); a2 = fdot2(wv[ 9], hx1, a2);
      a2 = fdot2(wv[10], hx2, a2); a2 = fdot2(wv[11], hx3, a2);
      a3 = fdot2(wv[12], hx0, a3); a3 = fdot2(wv[13], hx1, a3);
      a3 = fdot2(wv[14], hx2, a3); a3 = fdot2(wv[15], hx3, a3);
    }
    float ig = sigmoid_f(a0), fg = sigmoid_f(a1);
    float gg = tanh_f(a2),    og = sigmoid_f(a3);
    c = fg * c + ig * gg;
    float h = og * tanh_f(c);
    unsigned short hbits = __half_as_ushort(__float2half(h));
    hs[(size_t)(b * T_ + t) * H_ + l] = hbits;
    ((unsigned short*)hpair[(t & 1) ^ 1])[l] = hbits;
    __syncthreads();                               // h(t) visible to all waves
  }
}

// ---------------- K3: out = hs @ W_fc^T + b_fc ----------------
__global__ __launch_bounds__(256, 2) void k3_out(
    const unsigned short* __restrict__ hs, const unsigned int* __restrict__ wfcp,
    const float* __restrict__ bfc, float* __restrict__ out) {
  __shared__ unsigned int ht[64 * 128];            // 64 bt-rows of h (f16 pairs)
  const int l = threadIdx.x, blk = blockIdx.x;
  const unsigned int* hsrc = (const unsigned int*)hs + (size_t)blk * 64 * 128;
  for (int i = l; i < 64 * 128; i += 256) ht[i] = hsrc[i];
  __syncthreads();
  const int c1 = l;
  const int c2 = 256 + l;
  const bool has2 = (c2 < O_);
  const int c2r = has2 ? c2 : 0;
  float b1 = bfc[c1], b2 = bfc[c2r];
  for (int btc = 0; btc < 4; ++btc) {
    float a1[16], a2[16];
#pragma unroll
    for (int j = 0; j < 16; ++j) { a1[j] = b1; a2[j] = b2; }
    for (int Pc = 0; Pc < 8; ++Pc) {
      uint4 wq1[4], wq2[4];
#pragma unroll
      for (int p4 = 0; p4 < 4; ++p4) {
        wq1[p4] = *(const uint4*)&wfcp[c1 * 128 + Pc * 16 + 4 * p4];
        wq2[p4] = *(const uint4*)&wfcp[c2r * 128 + Pc * 16 + 4 * p4];
      }
#pragma unroll
      for (int j = 0; j < 16; ++j) {
        const unsigned int* hr = &ht[(btc * 16 + j) * 128 + Pc * 16];
#pragma unroll
        for (int p4 = 0; p4 < 4; ++p4) {
          uint4 hv = *(const uint4*)&hr[4 * p4];
          a1[j] = fdot2(wq1[p4].x, hv.x, a1[j]);
          a1[j] = fdot2(wq1[p4].y, hv.y, a1[j]);
          a1[j] = fdot2(wq1[p4].z, hv.z, a1[j]);
          a1[j] = fdot2(wq1[p4].w, hv.w, a1[j]);
          a2[j] = fdot2(wq2[p4].x, hv.x, a2[j]);
          a2[j] = fdot2(wq2[p4].y, hv.y, a2[j]);
          a2[j] = fdot2(wq2[p4].z, hv.z, a2[j]);
          a2[j] = fdot2(wq2[p4].w, hv.w, a2[j]);
        }
      }
    }
#pragma unroll
    for (int j = 0; j < 16; ++j) {
      size_t bt = (size_t)blk * 64 + btc * 16 + j;
      out[bt * O_ + c1] = a1[j];
      if (has2) out[bt * O_ + c2] = a2[j];
    }
  }
}

// ---------------- host ----------------
extern "C" void kernel_launch(void* const* d_in, const int* in_sizes, int n_in,
                              void* d_out, int out_size, void* d_ws, size_t ws_size,
                              hipStream_t stream) {
  const float* x   = (const float*)d_in[0];
  const float* wih = (const float*)d_in[1];
  const float* whh = (const float*)d_in[2];
  const float* bih = (const float*)d_in[3];
  const float* bhh = (const float*)d_in[4];
  const float* wfc = (const float*)d_in[5];
  const float* bfc = (const float*)d_in[6];
  float* out = (float*)d_out;
  char* ws = (char*)d_ws;

  const size_t HS_BYTES = (size_t)B_ * T_ * H_ * 2;
  const size_t XG_F32   = (size_t)B_ * T_ * G4_ * 4;
  const size_t WREG_B   = 100 * 256 * 16;
  const size_t WLDS_B   = 28 * 256 * 16;
  const size_t WPIH_B   = (size_t)IN_ * G4_ * 4;
  const size_t BIAS_B   = (size_t)G4_ * 4;
  const size_t WFCP_B   = (size_t)O_ * 128 * 4;
  const size_t TAIL = HS_BYTES + WREG_B + WLDS_B + WPIH_B + BIAS_B + WFCP_B;

  bool f32xg = (ws_size >= XG_F32 + TAIL);
  size_t xg_bytes = f32xg ? XG_F32 : ((size_t)B_ * T_ * G4_ * 2);

  char* xg    = ws;
  char* hsb   = ws + xg_bytes;
  char* wregp = hsb + HS_BYTES;
  char* wldsp = wregp + WREG_B;
  char* wpihp = wldsp + WLDS_B;
  char* biasp = wpihp + WPIH_B;
  char* wfcpp = biasp + BIAS_B;

  hipLaunchKernelGGL(k0_pack, dim3(957), dim3(256), 0, stream,
                     wih, whh, bih, bhh, wfc,
                     (float*)wpihp, (float*)biasp,
                     (unsigned int*)wregp, (unsigned int*)wldsp,
                     (unsigned int*)wfcpp);
  if (f32xg) {
    hipLaunchKernelGGL((k1_xgemm<true>), dim3(512), dim3(256), 0, stream,
                       x, (const float*)wpihp, (const float*)biasp, (void*)xg);
    hipLaunchKernelGGL((k2_lstm<true>), dim3(64), dim3(256), 0, stream,
                       (const void*)xg, (const uint4*)wregp, (const uint4*)wldsp,
                       (unsigned short*)hsb);
  } else {
    hipLaunchKernelGGL((k1_xgemm<false>), dim3(512), dim3(256), 0, stream,
                       x, (const float*)wpihp, (const float*)biasp, (void*)xg);
    hipLaunchKernelGGL((k2_lstm<false>), dim3(64), dim3(256), 0, stream,
                       (const void*)xg, (const uint4*)wregp, (const uint4*)wldsp,
                       (unsigned short*)hsb);
  }
  hipLaunchKernelGGL(k3_out, dim3(512), dim3(256), 0, stream,
                     (const unsigned short*)hsb, (const unsigned int*)wfcpp,
                     bfc, out);
}

// Round 4
// 981.489 us; speedup vs baseline: 1.7014x; 1.2950x over previous
//
#include <hip/hip_runtime.h>
#include <hip/hip_fp16.h>

typedef _Float16 half2v __attribute__((ext_vector_type(2)));

#define B_ 64
#define T_ 512
#define H_ 256
#define G4_ 1024
#define IN_ 60
#define O_ 402

__device__ __forceinline__ float fdot2(unsigned int a, unsigned int b, float c) {
  return __builtin_amdgcn_fdot2(__builtin_bit_cast(half2v, a),
                                __builtin_bit_cast(half2v, b), c, false);
}

__device__ __forceinline__ unsigned int pack_h2(float a, float b) {
  unsigned short ua = __half_as_ushort(__float2half(a));
  unsigned short ub = __half_as_ushort(__float2half(b));
  return (unsigned int)ua | ((unsigned int)ub << 16);
}

__device__ __forceinline__ float sigmoid_f(float x) {
  return __fdividef(1.0f, 1.0f + __expf(-x));
}
__device__ __forceinline__ float tanh_f(float x) {
  float ax = fminf(fabsf(x) * 2.0f, 40.0f);
  float e = __expf(ax);
  float r = __fdividef(e - 1.0f, e + 1.0f);
  return copysignf(r, x);
}

// ---------------- K0: weight packing / permutation ----------------
// xg gate-row permutation: packed col r' = 4*u + q  <->  original row q*256 + u
// W_hh layout for k2 (512 threads): thread l = (u = l>>1, hf = l&1) owns all 4
// gate rows of unit u over k-half hf. 16 chunks of 4 k-pairs each; chunks 0..11
// -> register stream, 12..15 -> LDS stream. Stream layout [(cc*4+q)*512 + l]
// as uint4 (4 consecutive k-pair dwords).
__global__ __launch_bounds__(256) void k0_pack(
    const float* __restrict__ wih, const float* __restrict__ whh,
    const float* __restrict__ bih, const float* __restrict__ bhh,
    const float* __restrict__ wfc,
    float* __restrict__ wpih, float* __restrict__ biasp,
    unsigned int* __restrict__ wreg_ws, unsigned int* __restrict__ wlds_ws,
    unsigned int* __restrict__ wfcp) {
  int idx = blockIdx.x * 256 + threadIdx.x;
  if (idx < 61440) {                       // Wp_ih[k][r'] = W_ih[orig(r')][k]
    int k = idx / 1024, rp = idx % 1024;
    int orig = (rp & 3) * 256 + (rp >> 2);
    wpih[idx] = wih[orig * IN_ + k];
  } else if (idx < 62464) {                // bias_p[r'] = b_ih[orig]+b_hh[orig]
    int rp = idx - 61440;
    int orig = (rp & 3) * 256 + (rp >> 2);
    biasp[rp] = bih[orig] + bhh[orig];
  } else if (idx < 193536) {               // W_hh -> f16 pairs, k2 layout
    int i2 = idx - 62464;                  // 0..131071
    int l = i2 >> 8;                       // k2 thread 0..511
    int i = i2 & 255;                      // dword within thread
    int cc = i >> 4, q = (i >> 2) & 3, p = i & 3;
    int u = l >> 1, hf = l & 1;
    int P = hf * 64 + cc * 4 + p;          // k-pair index: covers k=2P,2P+1
    int row = q * 256 + u;                 // original gate row
    unsigned int pk = pack_h2(whh[row * 256 + 2 * P], whh[row * 256 + 2 * P + 1]);
    if (cc < 12) wreg_ws[((cc * 4 + q) * 512 + l) * 4 + p] = pk;
    else         wlds_ws[(((cc - 12) * 4 + q) * 512 + l) * 4 + p] = pk;
  } else if (idx < 244992) {               // W_fc -> f16 pairs
    int i3 = idx - 193536;
    int o = i3 >> 7, P = i3 & 127;
    wfcp[o * 128 + P] = pack_h2(wfc[o * 256 + 2 * P], wfc[o * 256 + 2 * P + 1]);
  }
}

// ---------------- K1: xg = x @ W_ih^T + b_ih + b_hh (permuted cols) ---------
template <bool F32>
__global__ __launch_bounds__(256, 2) void k1_xgemm(
    const float* __restrict__ x, const float* __restrict__ wpih,
    const float* __restrict__ biasp, void* __restrict__ xg_v) {
  __shared__ float xt[IN_ * 64];           // xt[k][bt]
  const int l = threadIdx.x, blk = blockIdx.x;
  for (int i = l; i < IN_ * 64; i += 256) {
    int k = i >> 6, bt = i & 63;
    xt[i] = x[(size_t)(blk * 64 + bt) * IN_ + k];
  }
  __syncthreads();
  float4 bias4 = *(const float4*)&biasp[4 * l];
  float* xg_f = (float*)xg_v;
  unsigned int* xg_h = (unsigned int*)xg_v;
  for (int half = 0; half < 2; ++half) {   // 2 chunks of 32 bt-rows
    float4 a[32];
#pragma unroll
    for (int j = 0; j < 32; ++j) a[j] = bias4;
    for (int k = 0; k < IN_; ++k) {
      float4 w4 = *(const float4*)&wpih[k * G4_ + 4 * l];
#pragma unroll
      for (int j4 = 0; j4 < 8; ++j4) {
        float4 xv = *(const float4*)&xt[k * 64 + half * 32 + j4 * 4];
        float xs[4] = {xv.x, xv.y, xv.z, xv.w};
#pragma unroll
        for (int jj = 0; jj < 4; ++jj) {
          float xc = xs[jj];
          float4& A = a[j4 * 4 + jj];
          A.x = fmaf(w4.x, xc, A.x); A.y = fmaf(w4.y, xc, A.y);
          A.z = fmaf(w4.z, xc, A.z); A.w = fmaf(w4.w, xc, A.w);
        }
      }
    }
#pragma unroll
    for (int j = 0; j < 32; ++j) {
      size_t bt = (size_t)blk * 64 + half * 32 + j;
      if constexpr (F32) {
        *(float4*)&xg_f[bt * G4_ + 4 * l] = a[j];
      } else {
        uint2 pk;
        pk.x = pack_h2(a[j].x, a[j].y);
        pk.y = pack_h2(a[j].z, a[j].w);
        *(uint2*)&xg_h[bt * (G4_ / 2) + 2 * l] = pk;
      }
    }
  }
}

// ---------------- K2: sequential LSTM, 1 block per batch row ----------------
// 512 threads = 8 waves = 2 waves/SIMD (TLP latency hiding). Thread l =
// (unit u=l>>1, k-half hf=l&1): all 4 gates of unit u over 128 k values.
// Weights: 192 dwords in VGPRs (chunks 0..11) + 64 dwords in LDS (12..15).
// Partner lanes adjacent in same wave -> partial-sum combine via shfl_xor(1),
// no extra barrier. Both lanes gate redundantly; even lane publishes h.
template <bool F32>
__global__ __launch_bounds__(512, 2) void k2_lstm(
    const void* __restrict__ xg_v, const uint4* __restrict__ wreg_ws,
    const uint4* __restrict__ wlds_ws, unsigned short* __restrict__ hs) {
  __shared__ uint4 wlds[4 * 4 * 512];                   // 131072 B
  __shared__ __align__(16) unsigned short hbuf[2][256]; // h double buffer (f16)
  const int l = threadIdx.x;
  const int b = blockIdx.x;
  const int u = l >> 1, hf = l & 1;
  for (int i = l; i < 4 * 4 * 512; i += 512) wlds[i] = wlds_ws[i];
  if (l < 128) ((unsigned int*)hbuf)[l] = 0u;           // h(0) = 0

  uint4 wr[48];                                          // 192 VGPRs of weights
#pragma unroll
  for (int i = 0; i < 48; ++i) wr[i] = wreg_ws[i * 512 + l];

  const float4* xg4 = (const float4*)xg_v;               // [bt*256 + u]
  const uint2*  xg2 = (const uint2*)xg_v;                // [bt*256 + u]
  float4 xf; uint2 xh;
  if constexpr (F32) xf = xg4[(size_t)b * T_ * 256 + u];
  else               xh = xg2[(size_t)b * T_ * 256 + u];
  float c = 0.0f;
  __syncthreads();
  for (int t = 0; t < T_; ++t) {
    float a0, a1, a2, a3;
    if constexpr (F32) {
      a0 = hf ? 0.0f : xf.x; a1 = hf ? 0.0f : xf.y;
      a2 = hf ? 0.0f : xf.z; a3 = hf ? 0.0f : xf.w;
    } else {
      half2v p0 = __builtin_bit_cast(half2v, xh.x);
      half2v p1 = __builtin_bit_cast(half2v, xh.y);
      a0 = hf ? 0.0f : (float)p0[0]; a1 = hf ? 0.0f : (float)p0[1];
      a2 = hf ? 0.0f : (float)p1[0]; a3 = hf ? 0.0f : (float)p1[1];
    }
    int tn = (t < T_ - 1) ? (t + 1) : t;                 // prefetch next xg
    if constexpr (F32) xf = xg4[(size_t)(b * T_ + tn) * 256 + u];
    else               xh = xg2[(size_t)(b * T_ + tn) * 256 + u];

    const uint4* hB = (const uint4*)(&hbuf[t & 1][hf * 128]);  // 16 x uint4
#pragma unroll
    for (int cc = 0; cc < 16; ++cc) {
      uint4 hq = hB[cc];
      uint4 w0, w1, w2, w3;
      if (cc < 12) {
        w0 = wr[cc * 4 + 0]; w1 = wr[cc * 4 + 1];
        w2 = wr[cc * 4 + 2]; w3 = wr[cc * 4 + 3];
      } else {
        int c2 = cc - 12;
        w0 = wlds[(c2 * 4 + 0) * 512 + l];
        w1 = wlds[(c2 * 4 + 1) * 512 + l];
        w2 = wlds[(c2 * 4 + 2) * 512 + l];
        w3 = wlds[(c2 * 4 + 3) * 512 + l];
      }
      a0 = fdot2(w0.x, hq.x, a0); a0 = fdot2(w0.y, hq.y, a0);
      a0 = fdot2(w0.z, hq.z, a0); a0 = fdot2(w0.w, hq.w, a0);
      a1 = fdot2(w1.x, hq.x, a1); a1 = fdot2(w1.y, hq.y, a1);
      a1 = fdot2(w1.z, hq.z, a1); a1 = fdot2(w1.w, hq.w, a1);
      a2 = fdot2(w2.x, hq.x, a2); a2 = fdot2(w2.y, hq.y, a2);
      a2 = fdot2(w2.z, hq.z, a2); a2 = fdot2(w2.w, hq.w, a2);
      a3 = fdot2(w3.x, hq.x, a3); a3 = fdot2(w3.y, hq.y, a3);
      a3 = fdot2(w3.z, hq.z, a3); a3 = fdot2(w3.w, hq.w, a3);
    }
    // combine the two k-halves (partner lane in same wave)
    a0 += __shfl_xor(a0, 1); a1 += __shfl_xor(a1, 1);
    a2 += __shfl_xor(a2, 1); a3 += __shfl_xor(a3, 1);
    // gating (redundant on both lanes of the pair)
    float ig = sigmoid_f(a0), fg = sigmoid_f(a1);
    float gg = tanh_f(a2),    og = sigmoid_f(a3);
    c = fg * c + ig * gg;
    float h = og * tanh_f(c);
    unsigned short hbits = __half_as_ushort(__float2half(h));
    if (hf == 0) {
      hbuf[(t & 1) ^ 1][u] = hbits;
      hs[(size_t)(b * T_ + t) * H_ + u] = hbits;
    }
    __syncthreads();                                     // h(t) visible to all
  }
}

// ---------------- K3: out = hs @ W_fc^T + b_fc ----------------
__global__ __launch_bounds__(256, 2) void k3_out(
    const unsigned short* __restrict__ hs, const unsigned int* __restrict__ wfcp,
    const float* __restrict__ bfc, float* __restrict__ out) {
  __shared__ unsigned int ht[64 * 128];            // 64 bt-rows of h (f16 pairs)
  const int l = threadIdx.x, blk = blockIdx.x;
  const unsigned int* hsrc = (const unsigned int*)hs + (size_t)blk * 64 * 128;
  for (int i = l; i < 64 * 128; i += 256) ht[i] = hsrc[i];
  __syncthreads();
  const int c1 = l;
  const int c2 = 256 + l;
  const bool has2 = (c2 < O_);
  const int c2r = has2 ? c2 : 0;
  float b1 = bfc[c1], b2 = bfc[c2r];
  for (int btc = 0; btc < 4; ++btc) {
    float a1[16], a2[16];
#pragma unroll
    for (int j = 0; j < 16; ++j) { a1[j] = b1; a2[j] = b2; }
    for (int Pc = 0; Pc < 8; ++Pc) {
      uint4 wq1[4], wq2[4];
#pragma unroll
      for (int p4 = 0; p4 < 4; ++p4) {
        wq1[p4] = *(const uint4*)&wfcp[c1 * 128 + Pc * 16 + 4 * p4];
        wq2[p4] = *(const uint4*)&wfcp[c2r * 128 + Pc * 16 + 4 * p4];
      }
#pragma unroll
      for (int j = 0; j < 16; ++j) {
        const unsigned int* hr = &ht[(btc * 16 + j) * 128 + Pc * 16];
#pragma unroll
        for (int p4 = 0; p4 < 4; ++p4) {
          uint4 hv = *(const uint4*)&hr[4 * p4];
          a1[j] = fdot2(wq1[p4].x, hv.x, a1[j]);
          a1[j] = fdot2(wq1[p4].y, hv.y, a1[j]);
          a1[j] = fdot2(wq1[p4].z, hv.z, a1[j]);
          a1[j] = fdot2(wq1[p4].w, hv.w, a1[j]);
          a2[j] = fdot2(wq2[p4].x, hv.x, a2[j]);
          a2[j] = fdot2(wq2[p4].y, hv.y, a2[j]);
          a2[j] = fdot2(wq2[p4].z, hv.z, a2[j]);
          a2[j] = fdot2(wq2[p4].w, hv.w, a2[j]);
        }
      }
    }
#pragma unroll
    for (int j = 0; j < 16; ++j) {
      size_t bt = (size_t)blk * 64 + btc * 16 + j;
      out[bt * O_ + c1] = a1[j];
      if (has2) out[bt * O_ + c2] = a2[j];
    }
  }
}

// ---------------- host ----------------
extern "C" void kernel_launch(void* const* d_in, const int* in_sizes, int n_in,
                              void* d_out, int out_size, void* d_ws, size_t ws_size,
                              hipStream_t stream) {
  const float* x   = (const float*)d_in[0];
  const float* wih = (const float*)d_in[1];
  const float* whh = (const float*)d_in[2];
  const float* bih = (const float*)d_in[3];
  const float* bhh = (const float*)d_in[4];
  const float* wfc = (const float*)d_in[5];
  const float* bfc = (const float*)d_in[6];
  float* out = (float*)d_out;
  char* ws = (char*)d_ws;

  const size_t HS_BYTES = (size_t)B_ * T_ * H_ * 2;
  const size_t XG_F32   = (size_t)B_ * T_ * G4_ * 4;
  const size_t WREG_B   = 12 * 4 * 512 * 16;   // 393216
  const size_t WLDS_B   = 4 * 4 * 512 * 16;    // 131072
  const size_t WPIH_B   = (size_t)IN_ * G4_ * 4;
  const size_t BIAS_B   = (size_t)G4_ * 4;
  const size_t WFCP_B   = (size_t)O_ * 128 * 4;
  const size_t TAIL = HS_BYTES + WREG_B + WLDS_B + WPIH_B + BIAS_B + WFCP_B;

  bool f32xg = (ws_size >= XG_F32 + TAIL);
  size_t xg_bytes = f32xg ? XG_F32 : ((size_t)B_ * T_ * G4_ * 2);

  char* xg    = ws;
  char* hsb   = ws + xg_bytes;
  char* wregp = hsb + HS_BYTES;
  char* wldsp = wregp + WREG_B;
  char* wpihp = wldsp + WLDS_B;
  char* biasp = wpihp + WPIH_B;
  char* wfcpp = biasp + BIAS_B;

  hipLaunchKernelGGL(k0_pack, dim3(957), dim3(256), 0, stream,
                     wih, whh, bih, bhh, wfc,
                     (float*)wpihp, (float*)biasp,
                     (unsigned int*)wregp, (unsigned int*)wldsp,
                     (unsigned int*)wfcpp);
  if (f32xg) {
    hipLaunchKernelGGL((k1_xgemm<true>), dim3(512), dim3(256), 0, stream,
                       x, (const float*)wpihp, (const float*)biasp, (void*)xg);
    hipLaunchKernelGGL((k2_lstm<true>), dim3(64), dim3(512), 0, stream,
                       (const void*)xg, (const uint4*)wregp, (const uint4*)wldsp,
                       (unsigned short*)hsb);
  } else {
    hipLaunchKernelGGL((k1_xgemm<false>), dim3(512), dim3(256), 0, stream,
                       x, (const float*)wpihp, (const float*)biasp, (void*)xg);
    hipLaunchKernelGGL((k2_lstm<false>), dim3(64), dim3(512), 0, stream,
                       (const void*)xg, (const uint4*)wregp, (const uint4*)wldsp,
                       (unsigned short*)hsb);
  }
  hipLaunchKernelGGL(k3_out, dim3(512), dim3(256), 0, stream,
                     (const unsigned short*)hsb, (const unsigned int*)wfcpp,
                     bfc, out);
}